// Round 13
// baseline (555.624 us; speedup 1.0000x reference)
//
#include <hip/hip_runtime.h>

#define HH 96
#define WW 128
#define PP 9
#define RAD 4
#define YT 2                    // y rows per block
#define CCH 8                   // channels per chunk
#define NCHUNK 16
#define ROWS2 (YT + PP - 1)     // 10 in2 rows staged (all 9 di in-block)
#define WB 64                   // x-tile width per block
#define HALO (WB + 2 * RAD)     // 72 in2 granules per row
#define GS2 73                  // in2 granule row stride (+1 pad)
#define GS1 65                  // in1 granule row stride (+1 pad)
#define NP2 (ROWS2 * (HALO / 2))    // 360 in2 granule-pairs
#define NP1 (YT * (WB / 2))         // 64 in1 granule-pairs
#define NTASK (NP2 + NP1)           // 424 staging tasks (<= NT)
#define NT 576                  // 9 waves: di = tid>>6 (wave-uniform)
#define CHS (HH * WW)           // channel plane stride
#define CSTEP (CCH * CHS)       // global stride per chunk

// clang's amdgcn builtins use __fp16 vectors ('h' encoding), not _Float16.
typedef __fp16 h2v __attribute__((ext_vector_type(2)));
union HU { unsigned int u; h2v h; };

__device__ __forceinline__ unsigned int pk(float a, float b) {
    HU r; r.h = __builtin_amdgcn_cvt_pkrtz(a, b); return r.u;
}
__device__ __forceinline__ float dot2(unsigned int a, unsigned int b, float c) {
    HU ua, ub; ua.u = a; ub.u = b;
    return __builtin_amdgcn_fdot2(ua.h, ub.h, c, false);
}
// granule-level XOR swizzle: spreads strided granule reads across bank groups
__device__ __forceinline__ int swz(int g) { return g ^ ((g >> 3) & 7); }

__global__ __launch_bounds__(NT, 7)
void corr_kernel(const float* __restrict__ in1, const float* __restrict__ in2,
                 float* __restrict__ out)
{
    // double-buffered LDS; one barrier per chunk
    __shared__ uint4 s2[2][ROWS2 * GS2];   // in2 window rows (10 per buf)
    __shared__ uint4 s1[2][YT * GS1];      // in1 rows

    const int tid = threadIdx.x;
    const int by  = blockIdx.x >> 1;       // y-tile
    const int bx  = blockIdx.x & 1;        // x-tile
    const int y0  = by * YT;
    const int x0b = bx * WB;
    const int b   = blockIdx.y;

    // compute role: di wave-uniform (tid>>6), then yl, xg
    const int di  = tid >> 6;              // 0..8
    const int yl  = (tid >> 5) & 1;        // 0..1
    const int xg  = tid & 31;              // 0..31
    const int x0l = 2 * xg;                // local x of first pixel

    const float* b1 = in1 + (size_t)b * 128 * CHS;
    const float* b2 = in2 + (size_t)b * 128 * CHS;

    // ---- staging task: one granule-PAIR per thread (424 tasks) ----
    // RAD=4 even + gx even => both pair halves share one validity predicate.
    const bool act = (tid < NTASK);
    const float* tp = b1; int dA = 0, dB = 0; bool tv = false, is2 = false;
    if (tid < NP2) {                       // in2: row = tid/36, pair = tid%36
        const int r  = tid / 36;
        const int p  = tid - r * 36;
        const int gy = y0 - RAD + r;
        const int gx = x0b + 2 * p - RAD;
        is2 = true;
        tv  = ((unsigned)gy < HH) && ((unsigned)gx < WW);
        tp  = b2 + (gy * WW + gx);
        dA  = r * GS2 + swz(2 * p);
        dB  = r * GS2 + swz(2 * p + 1);
    } else if (act) {                      // in1: u in [0,64)
        const int u = tid - NP2;
        const int r = u >> 5;
        const int p = u & 31;
        tv  = true;
        tp  = b1 + ((y0 + r) * WW + x0b + 2 * p);
        dA  = r * GS1 + swz(2 * p);
        dB  = r * GS1 + swz(2 * p + 1);
    }

    float acc[PP][2];
    #pragma unroll
    for (int j = 0; j < PP; ++j) { acc[j][0] = 0.f; acc[j][1] = 0.f; }

    // T14 prefetch state: 8 NAMED float2 (16 VGPR) — no arrays, no spill.
    float2 f0, f1, f2, f3, f4, f5, f6, f7;

#define ISSUE(co_) do {                                                        \
    f0 = tv ? *reinterpret_cast<const float2*>(tp + (co_) + 0 * CHS) : make_float2(0.f, 0.f); \
    f1 = tv ? *reinterpret_cast<const float2*>(tp + (co_) + 1 * CHS) : make_float2(0.f, 0.f); \
    f2 = tv ? *reinterpret_cast<const float2*>(tp + (co_) + 2 * CHS) : make_float2(0.f, 0.f); \
    f3 = tv ? *reinterpret_cast<const float2*>(tp + (co_) + 3 * CHS) : make_float2(0.f, 0.f); \
    f4 = tv ? *reinterpret_cast<const float2*>(tp + (co_) + 4 * CHS) : make_float2(0.f, 0.f); \
    f5 = tv ? *reinterpret_cast<const float2*>(tp + (co_) + 5 * CHS) : make_float2(0.f, 0.f); \
    f6 = tv ? *reinterpret_cast<const float2*>(tp + (co_) + 6 * CHS) : make_float2(0.f, 0.f); \
    f7 = tv ? *reinterpret_cast<const float2*>(tp + (co_) + 7 * CHS) : make_float2(0.f, 0.f); \
} while (0)

#define LANDIT(buf_) do {                                                      \
    uint4 gA, gB;                                                              \
    gA.x = pk(f0.x, f1.x); gA.y = pk(f2.x, f3.x);                              \
    gA.z = pk(f4.x, f5.x); gA.w = pk(f6.x, f7.x);                              \
    gB.x = pk(f0.y, f1.y); gB.y = pk(f2.y, f3.y);                              \
    gB.z = pk(f4.y, f5.y); gB.w = pk(f6.y, f7.y);                              \
    if (is2) { s2[buf_][dA] = gA; s2[buf_][dB] = gB; }                         \
    else     { s1[buf_][dA] = gA; s1[buf_][dB] = gB; }                         \
} while (0)

    // ---- prologue: stage chunk 0 into buf 0 ----
    if (act) { ISSUE(0); LANDIT(0); }
    __syncthreads();

    for (int cc = 0; cc < NCHUNK; ++cc) {
        const int buf = cc & 1;
        const bool more = (cc + 1 < NCHUNK);

        // issue-early: next chunk's global loads go in flight now
        if (more && act) ISSUE((cc + 1) * CSTEP);

        // compute chunk cc from LDS (hides the load latency above)
        {
            const uint4* ar = &s1[buf][yl * GS1];
            const uint4 a0 = ar[swz(x0l)];
            const uint4 a1 = ar[swz(x0l + 1)];
            const uint4* r2 = &s2[buf][(yl + di) * GS2];
            #pragma unroll
            for (int w = 0; w < PP + 1; ++w) {      // 10-granule window
                const uint4 v = r2[swz(x0l + w)];
                if (w <= PP - 1) {
                    float t = acc[w][0];
                    t = dot2(v.x, a0.x, t); t = dot2(v.y, a0.y, t);
                    t = dot2(v.z, a0.z, t); t = dot2(v.w, a0.w, t);
                    acc[w][0] = t;
                }
                if (w >= 1) {
                    float t = acc[w - 1][1];
                    t = dot2(v.x, a1.x, t); t = dot2(v.y, a1.y, t);
                    t = dot2(v.z, a1.z, t); t = dot2(v.w, a1.w, t);
                    acc[w - 1][1] = t;
                }
            }
        }

        // write-late: land chunk cc+1 into the other buffer
        if (more && act) LANDIT(buf ^ 1);
        __syncthreads();
        // barrier orders: my buf^1 writes visible before anyone computes
        // cc+1; readers of buf finished before next iter's writes touch it.
    }

    // ---- epilogue: disjoint float2 stores ----
    const int y  = y0 + yl;
    const int xo = x0b + x0l;
    #pragma unroll
    for (int dj = 0; dj < PP; ++dj) {
        float* op = out + ((((size_t)(b * PP + di)) * PP + dj) * HH + y) * WW + xo;
        *reinterpret_cast<float2*>(op) = make_float2(acc[dj][0], acc[dj][1]);
    }
}

extern "C" void kernel_launch(void* const* d_in, const int* in_sizes, int n_in,
                              void* d_out, int out_size, void* d_ws, size_t ws_size,
                              hipStream_t stream) {
    const float* in1 = (const float*)d_in[0];
    const float* in2 = (const float*)d_in[1];
    float* out = (float*)d_out;
    dim3 grid((HH / YT) * 2, 8);   // 96 x 8 = 768 blocks = exactly 3/CU
    dim3 block(NT);
    corr_kernel<<<grid, block, 0, stream>>>(in1, in2, out);
}